// Round 17
// baseline (543.963 us; speedup 1.0000x reference)
//
#include <hip/hip_runtime.h>
#include <hip/hip_fp16.h>

#define LRELU(v) ((v) >= 0.f ? (v) : 0.2f * (v))
#define DLRELU(v) ((v) >= 0.f ? (v) : 0.04f * (v))

constexpr int Nn = 50000;
constexpr int Ee = 800000;
constexpr int Hh = 256;
constexpr int Gg = 128;
constexpr int Oo = 10;

typedef __attribute__((ext_vector_type(8))) short short8;
typedef __attribute__((ext_vector_type(4))) float f32x4;
typedef __attribute__((ext_vector_type(4))) float fv4;
typedef __attribute__((ext_vector_type(4))) unsigned int uv4;
typedef __attribute__((ext_vector_type(2))) unsigned int uv2;
typedef __attribute__((ext_vector_type(4))) unsigned short us4;

__device__ inline unsigned short f2h(float f) {
  __half h = __float2half_rn(f);
  return *reinterpret_cast<unsigned short*>(&h);
}
__device__ inline float h2f(unsigned short u) {
  __half h = *reinterpret_cast<__half*>(&u);
  return __half2float(h);
}
__device__ inline __half2 u2h2(unsigned int u) {
  return *reinterpret_cast<__half2*>(&u);
}
__device__ inline unsigned int h22u(__half2 h) {
  return *reinterpret_cast<unsigned int*>(&h);
}
__device__ inline __half2 hmax2(__half2 a, __half2 b) {
  __half2 r;
  asm volatile("v_pk_max_f16 %0, %1, %2" : "=v"(r) : "v"(a), "v"(b));
  return r;
}
__device__ inline unsigned short f2bf(float f) {
  union { float f; unsigned int i; } v; v.f = f;
  unsigned int i = v.i;
  return (unsigned short)((i + 0x7FFFu + ((i >> 16) & 1u)) >> 16);
}

typedef __attribute__((address_space(1))) const unsigned int gu32;
typedef __attribute__((address_space(3))) unsigned int lu32;
__device__ inline void gload_lds16(const void* g, void* l) {
  __builtin_amdgcn_global_load_lds((gu32*)g, (lu32*)l, 16, 0, 0);
}

// ---------------------------------------------------------------------------
// Consolidated prep: f2h(x) + hist + 10 weight transposes in ONE launch
// ---------------------------------------------------------------------------
struct PrepArgs {
  const float* x; unsigned short* x0h;
  const int* dst; int* deg;
  const float* wsrc[10];
  unsigned short* wdst[10];
  int K[10], M[10], Kpad[10], isbf[10], blk0[11];
};
constexpr int PREP_A = (Nn * 128 / 4 + 255) / 256;   // 6250
constexpr int PREP_B = (Ee + 255) / 256;             // 3125

__global__ __launch_bounds__(256) void prep_kernel(PrepArgs P)
{
  const int bid = blockIdx.x;
  if (bid < PREP_A) {
    const int i = bid * 256 + threadIdx.x;
    if (i >= Nn * 128 / 4) return;
    const fv4 v = __builtin_nontemporal_load(
        reinterpret_cast<const fv4*>(P.x) + i);
    us4 o; o.x = f2h(v.x); o.y = f2h(v.y); o.z = f2h(v.z); o.w = f2h(v.w);
    __builtin_nontemporal_store(o, reinterpret_cast<us4*>(P.x0h) + i);
    return;
  }
  if (bid < PREP_A + PREP_B) {
    const int e = (bid - PREP_A) * 256 + threadIdx.x;
    if (e < Ee) atomicAdd(&P.deg[P.dst[e]], 1);
    return;
  }
  int j = 0;
  #pragma unroll
  for (int q = 1; q < 10; q++) if (bid >= P.blk0[q]) j = q;
  const int g = (bid - P.blk0[j]) * 256 + threadIdx.x;
  const int Kpad = P.Kpad[j];
  if (g >= 256 * Kpad) return;
  const int c = g / Kpad, k = g % Kpad;
  unsigned short o = 0;
  if (c < P.M[j] && k < P.K[j]) {
    const float w = P.wsrc[j][(size_t)k * P.M[j] + c];
    o = P.isbf[j] ? f2bf(w) : f2h(w);
  }
  P.wdst[j][(size_t)c * Kpad + k] = o;
}

// ---------------------------------------------------------------------------
// CSR scan (scan2 folded into scan3) + fill
// ---------------------------------------------------------------------------
__global__ __launch_bounds__(1024) void scan1_kernel(
    const int* __restrict__ deg, int* __restrict__ bsum)
{
  const int i = blockIdx.x * 1024 + threadIdx.x;
  int v = (i < Nn) ? deg[i] : 0;
  #pragma unroll
  for (int o = 32; o; o >>= 1) v += __shfl_xor(v, o, 64);
  __shared__ int ws[16];
  const int wid = threadIdx.x >> 6, lane = threadIdx.x & 63;
  if (lane == 0) ws[wid] = v;
  __syncthreads();
  if (threadIdx.x == 0) {
    int s = 0;
    #pragma unroll
    for (int k = 0; k < 16; k++) s += ws[k];
    bsum[blockIdx.x] = s;
  }
}

__global__ __launch_bounds__(1024) void scan3_kernel(
    const int* __restrict__ deg, const int* __restrict__ bsum,
    int* __restrict__ row_ptr, int* __restrict__ cursor, int nb)
{
  // per-block prefix of bsum (tiny: <=49 entries, L2-hot)
  __shared__ int boffs;
  __shared__ int ws[16];
  if (threadIdx.x == 0) {
    int s = 0;
    for (int b = 0; b < (int)blockIdx.x; b++) s += bsum[b];
    boffs = s;
  }
  const int i = blockIdx.x * 1024 + threadIdx.x;
  const int wid = threadIdx.x >> 6, lane = threadIdx.x & 63;
  const int v = (i < Nn) ? deg[i] : 0;
  int inc = v;
  #pragma unroll
  for (int o = 1; o < 64; o <<= 1) {
    const int u = __shfl_up(inc, o, 64);
    if (lane >= o) inc += u;
  }
  if (lane == 63) ws[wid] = inc;
  __syncthreads();
  if (wid == 0 && lane < 16) {
    int s = ws[lane];
    #pragma unroll
    for (int o = 1; o < 16; o <<= 1) {
      const int u = __shfl_up(s, o, 64);
      if (lane >= o) s += u;
    }
    ws[lane] = s;
  }
  __syncthreads();
  const int woff = (wid == 0) ? 0 : ws[wid - 1];
  const int excl = boffs + woff + inc - v;
  if (i < Nn) { row_ptr[i] = excl; cursor[i] = excl; }
  if (i == Nn - 1) row_ptr[Nn] = excl + v;
}

__global__ __launch_bounds__(256) void fill_kernel(
    const int* __restrict__ src, const int* __restrict__ dst,
    const float* __restrict__ ea, int* __restrict__ cursor,
    uv4* __restrict__ edges)
{
  const int e = blockIdx.x * 256 + threadIdx.x;
  if (e >= Ee) return;
  const int pos = atomicAdd(&cursor[dst[e]], 1);
  uv4 r;
  r.x = (unsigned)src[e];
  r.y = h22u(__float2half2_rn(ea[3 * e + 0]));
  r.z = h22u(__float2half2_rn(ea[3 * e + 1]));
  r.w = h22u(__float2half2_rn(ea[3 * e + 2]));
  __builtin_nontemporal_store(r, edges + pos);
}

// ---------------------------------------------------------------------------
// Gather aggregation: fp16 packed math, 4 independent chains in flight
// ---------------------------------------------------------------------------
template<int DIN>
__global__ __launch_bounds__(256) void agg_gather(
    const unsigned short* __restrict__ x, const uv4* __restrict__ edges,
    const float* __restrict__ We, const float* __restrict__ be,
    const int* __restrict__ row_ptr, unsigned short* __restrict__ S)
{
  constexpr int FPL = DIN / 64;
  constexpr int H2  = FPL / 2;
  constexpr int SH  = (DIN == 256) ? 8 : 7;
  const int wv   = threadIdx.x >> 6;
  const int lane = threadIdx.x & 63;
  const int n = blockIdx.x * 4 + wv;
  if (n >= Nn) return;
  const int fo = lane * FPL;

  const __half2 zero2 = __float2half2_rn(0.f);
  __half2 w0h[H2], w1h[H2], w2h[H2], bbh[H2], acc[H2];
  #pragma unroll
  for (int j = 0; j < H2; j++) {
    w0h[j] = __halves2half2(__float2half_rn(We[0 * DIN + fo + 2 * j]),
                            __float2half_rn(We[0 * DIN + fo + 2 * j + 1]));
    w1h[j] = __halves2half2(__float2half_rn(We[1 * DIN + fo + 2 * j]),
                            __float2half_rn(We[1 * DIN + fo + 2 * j + 1]));
    w2h[j] = __halves2half2(__float2half_rn(We[2 * DIN + fo + 2 * j]),
                            __float2half_rn(We[2 * DIN + fo + 2 * j + 1]));
    bbh[j] = __halves2half2(__float2half_rn(be[fo + 2 * j]),
                            __float2half_rn(be[fo + 2 * j + 1]));
    acc[j] = zero2;
  }

  const int beg = row_ptr[n], end = row_ptr[n + 1];
  int i = beg;

  for (; i + 4 <= end; i += 4) {
    uv4 e[4];
    #pragma unroll
    for (int q = 0; q < 4; q++) e[q] = __builtin_nontemporal_load(edges + i + q);
    __half2 xv[4][H2];
    #pragma unroll
    for (int q = 0; q < 4; q++) {
      const unsigned o = (e[q].x << SH) + fo;
      if constexpr (H2 == 2) {
        const uv2 r = *reinterpret_cast<const uv2*>(x + o);
        xv[q][0] = u2h2(r.x); xv[q][1] = u2h2(r.y);
      } else {
        xv[q][0] = u2h2(*reinterpret_cast<const unsigned int*>(x + o));
      }
    }
    #pragma unroll
    for (int q = 0; q < 4; q++) {
      const __half2 a0 = u2h2(e[q].y), a1 = u2h2(e[q].z), a2 = u2h2(e[q].w);
      #pragma unroll
      for (int j = 0; j < H2; j++) {
        __half2 m = __hadd2(xv[q][j], bbh[j]);
        m = __hfma2(a2, w2h[j], m);
        m = __hfma2(a1, w1h[j], m);
        m = __hfma2(a0, w0h[j], m);
        acc[j] = __hadd2(acc[j], hmax2(m, zero2));
      }
    }
  }
  for (; i < end; i++) {
    const uv4 e0 = __builtin_nontemporal_load(edges + i);
    const unsigned o0 = (e0.x << SH) + fo;
    __half2 xv0[H2];
    if constexpr (H2 == 2) {
      const uv2 r0 = *reinterpret_cast<const uv2*>(x + o0);
      xv0[0] = u2h2(r0.x); xv0[1] = u2h2(r0.y);
    } else {
      xv0[0] = u2h2(*reinterpret_cast<const unsigned int*>(x + o0));
    }
    const __half2 a00 = u2h2(e0.y), a01 = u2h2(e0.z), a02 = u2h2(e0.w);
    #pragma unroll
    for (int j = 0; j < H2; j++) {
      __half2 m0 = __hadd2(xv0[j], bbh[j]);
      m0 = __hfma2(a02, w2h[j], m0);
      m0 = __hfma2(a01, w1h[j], m0);
      m0 = __hfma2(a00, w0h[j], m0);
      acc[j] = __hadd2(acc[j], hmax2(m0, zero2));
    }
  }

  const unsigned on = ((unsigned)n << SH) + fo;
  if constexpr (H2 == 2) {
    const uv2 rs = *reinterpret_cast<const uv2*>(x + on);
    const float2 s0 = __half22float2(u2h2(rs.x)), s1 = __half22float2(u2h2(rs.y));
    const float2 f0 = __half22float2(acc[0]), f1 = __half22float2(acc[1]);
    uv2 o;
    o.x = (unsigned)f2h(s0.x + f0.x) | ((unsigned)f2h(s0.y + f0.y) << 16);
    o.y = (unsigned)f2h(s1.x + f1.x) | ((unsigned)f2h(s1.y + f1.y) << 16);
    __builtin_nontemporal_store(o, reinterpret_cast<uv2*>(S + on));
  } else {
    const float2 s0 = __half22float2(u2h2(*reinterpret_cast<const unsigned int*>(x + on)));
    const float2 f0 = __half22float2(acc[0]);
    const unsigned o = (unsigned)f2h(s0.x + f0.x) | ((unsigned)f2h(s0.y + f0.y) << 16);
    __builtin_nontemporal_store(o, reinterpret_cast<unsigned int*>(S + on));
  }
}

// ---------------------------------------------------------------------------
// Fused dual GEMM + pooling (fp16)
// ---------------------------------------------------------------------------
template<int K1, bool WRITE_XB>
__global__ __launch_bounds__(512) void gemm12(
    const unsigned short* __restrict__ A,
    const unsigned short* __restrict__ B1t, const float* __restrict__ b1,
    const float* __restrict__ gamma, const float* __restrict__ beta,
    const float* __restrict__ mu, const float* __restrict__ var,
    const unsigned short* __restrict__ B2t, const float* __restrict__ b2,
    unsigned short* __restrict__ XB,
    const int* __restrict__ batch, float* __restrict__ pooled, int layer)
{
  __shared__ __align__(16) unsigned short smem[128 * 256];  // 64 KB
  unsigned short* lA = smem;
  unsigned short* lY = smem;
  float* part = (float*)smem;

  const int t = threadIdx.x;
  const int lane = t & 63, wid = t >> 6;
  const int wrow = wid >> 2, wcol = wid & 3;
  const int l15 = lane & 15, hi = lane >> 4;
  const int n0 = blockIdx.x * 128;

  // ---- stage full A tile [128][K1] ----
  constexpr int SPR = K1 / 8;
  constexpr int NCH = 128 * K1 * 2 / 1024;
  constexpr int CPW = NCH / 8;
  #pragma unroll
  for (int c = 0; c < CPW; c++) {
    const int ch = wid * CPW + c;
    const int row = ch * (512 / K1) + lane / SPR;
    const int slot = lane % SPR;
    const int scol = (slot ^ (row & 7)) * 8;
    const int gr = min(n0 + row, Nn - 1);
    gload_lds16(A + (size_t)gr * K1 + scol, (char*)lA + ch * 1024);
  }
  __syncthreads();

  // ---- phase 1: acc = A @ W1 ----
  f32x4 acc[4][4] = {};
  #pragma unroll
  for (int ks = 0; ks < K1 / 32; ks++) {
    short8 av[4], bv[4];
    #pragma unroll
    for (int rf = 0; rf < 4; rf++) {
      const int ar = wrow * 64 + rf * 16 + l15;
      av[rf] = *reinterpret_cast<const short8*>(
          (const char*)lA + ar * (K1 * 2) + (((ks * 4 + hi) ^ (ar & 7)) << 4));
    }
    #pragma unroll
    for (int cf = 0; cf < 4; cf++) {
      const int c = wcol * 64 + cf * 16 + l15;
      bv[cf] = *reinterpret_cast<const short8*>(B1t + (size_t)c * K1 + ks * 32 + hi * 8);
    }
    #pragma unroll
    for (int rf = 0; rf < 4; rf++)
      #pragma unroll
      for (int cf = 0; cf < 4; cf++)
        acc[rf][cf] = __builtin_amdgcn_mfma_f32_16x16x32_f16(av[rf], bv[cf], acc[rf][cf], 0, 0, 0);
  }
  __syncthreads();

  // ---- epilogue 1: BN + leaky -> lY ----
  #pragma unroll
  for (int cf = 0; cf < 4; cf++) {
    const int c = wcol * 64 + cf * 16 + l15;
    const float bs = b1[c];
    const float gm = gamma[c], bt2 = beta[c], mm = mu[c];
    const float iv = rsqrtf(var[c] + 1e-5f);
    const int slot0 = c >> 3;
    #pragma unroll
    for (int rf = 0; rf < 4; rf++)
      #pragma unroll
      for (int rg = 0; rg < 4; rg++) {
        const int row = wrow * 64 + rf * 16 + hi * 4 + rg;
        float v = acc[rf][cf][rg] + bs;
        v = gm * (v - mm) * iv + bt2;
        v = LRELU(v);
        *reinterpret_cast<unsigned short*>(
            (char*)lY + row * 512 + (((slot0 ^ (row & 7)) << 4)) + (c & 7) * 2) = f2h(v);
      }
  }
  __syncthreads();

  // prefetch pool slots early (hidden under phase-2 MFMAs)
  const int base = batch[min(n0, Nn - 1)];
  int slotArr[4][4];
  #pragma unroll
  for (int rf = 0; rf < 4; rf++)
    #pragma unroll
    for (int rg = 0; rg < 4; rg++) {
      const int row = n0 + wrow * 64 + rf * 16 + hi * 4 + rg;
      slotArr[rf][rg] = (row < Nn) ? (batch[row] - base) : -1;
    }

  // ---- phase 2: acc = Y @ W2 ----
  #pragma unroll
  for (int rf = 0; rf < 4; rf++)
    #pragma unroll
    for (int cf = 0; cf < 4; cf++) acc[rf][cf] = (f32x4){0.f, 0.f, 0.f, 0.f};
  #pragma unroll
  for (int ks = 0; ks < 8; ks++) {
    short8 av[4], bv[4];
    #pragma unroll
    for (int rf = 0; rf < 4; rf++) {
      const int ar = wrow * 64 + rf * 16 + l15;
      av[rf] = *reinterpret_cast<const short8*>(
          (const char*)lY + ar * 512 + (((ks * 4 + hi) ^ (ar & 7)) << 4));
    }
    #pragma unroll
    for (int cf = 0; cf < 4; cf++) {
      const int c = wcol * 64 + cf * 16 + l15;
      bv[cf] = *reinterpret_cast<const short8*>(B2t + (size_t)c * 256 + ks * 32 + hi * 8);
    }
    #pragma unroll
    for (int rf = 0; rf < 4; rf++)
      #pragma unroll
      for (int cf = 0; cf < 4; cf++)
        acc[rf][cf] = __builtin_amdgcn_mfma_f32_16x16x32_f16(av[rf], bv[cf], acc[rf][cf], 0, 0, 0);
  }
  __syncthreads();

  for (int z = t; z < 1024; z += 512) part[z] = 0.f;
  __syncthreads();

  // ---- epilogue 2 ----
  #pragma unroll
  for (int cf = 0; cf < 4; cf++) {
    const int col = wcol * 64 + cf * 16 + l15;
    const float bs = b2[col];
    float psum[4] = {0.f, 0.f, 0.f, 0.f};
    #pragma unroll
    for (int rf = 0; rf < 4; rf++)
      #pragma unroll
      for (int rg = 0; rg < 4; rg++) {
        const int sl = slotArr[rf][rg];
        if (sl < 0) continue;
        const float v = LRELU(acc[rf][cf][rg] + bs);
        if (WRITE_XB) {
          const int row = n0 + wrow * 64 + rf * 16 + hi * 4 + rg;
          XB[(size_t)row * 256 + col] = f2h(v);
        }
        psum[sl] += v;
      }
    #pragma unroll
    for (int k = 0; k < 4; k++)
      if (psum[k] != 0.f) atomicAdd(&part[k * 256 + col], psum[k]);
  }
  __syncthreads();

  for (int z = t; z < 1024; z += 512) {
    const float v = part[z];
    if (v != 0.f) {
      const int g = base + (z >> 8);
      if (g < Gg)
        atomicAdd(&pooled[(size_t)g * 768 + layer * 256 + (z & 255)], v);
    }
  }
}

// ---------------------------------------------------------------------------
// Fused MFMA head (BF16, reads fp32 pooled directly): 4 blocks x 32 graphs
// ---------------------------------------------------------------------------
__global__ __launch_bounds__(256) void head_fused(
    const float* __restrict__ P,
    const unsigned short* __restrict__ B1t,
    const unsigned short* __restrict__ B2t,
    const unsigned short* __restrict__ B3t,
    const unsigned short* __restrict__ B4t,
    const float* __restrict__ b1, const float* __restrict__ b2,
    const float* __restrict__ b3, const float* __restrict__ b4,
    float* __restrict__ out)
{
  __shared__ __align__(16) unsigned short act[32 * 256];
  const int t = threadIdx.x, lane = t & 63, wid = t >> 6;
  const int l15 = lane & 15, hi = lane >> 4;
  const int r0 = blockIdx.x * 32;

  f32x4 acc[2][4];

  #pragma unroll
  for (int rf = 0; rf < 2; rf++)
    #pragma unroll
    for (int cf = 0; cf < 4; cf++) acc[rf][cf] = (f32x4){0.f, 0.f, 0.f, 0.f};
  for (int ks = 0; ks < 24; ks++) {
    short8 bv[4], av[2];
    #pragma unroll
    for (int cf = 0; cf < 4; cf++) {
      const int c = wid * 64 + cf * 16 + l15;
      bv[cf] = *reinterpret_cast<const short8*>(B1t + (size_t)c * 768 + ks * 32 + hi * 8);
    }
    #pragma unroll
    for (int rf = 0; rf < 2; rf++) {
      const float* p = P + (size_t)(r0 + rf * 16 + l15) * 768 + ks * 32 + hi * 8;
      const float4 p0 = *reinterpret_cast<const float4*>(p);
      const float4 p1 = *reinterpret_cast<const float4*>(p + 4);
      short8 a;
      a[0] = (short)f2bf(p0.x); a[1] = (short)f2bf(p0.y);
      a[2] = (short)f2bf(p0.z); a[3] = (short)f2bf(p0.w);
      a[4] = (short)f2bf(p1.x); a[5] = (short)f2bf(p1.y);
      a[6] = (short)f2bf(p1.z); a[7] = (short)f2bf(p1.w);
      av[rf] = a;
    }
    #pragma unroll
    for (int rf = 0; rf < 2; rf++)
      #pragma unroll
      for (int cf = 0; cf < 4; cf++)
        acc[rf][cf] = __builtin_amdgcn_mfma_f32_16x16x32_bf16(av[rf], bv[cf], acc[rf][cf], 0, 0, 0);
  }
  #pragma unroll
  for (int cf = 0; cf < 4; cf++) {
    const int c = wid * 64 + cf * 16 + l15;
    const float bs = (c < 200) ? b1[c] : 0.f;
    const int slot0 = c >> 3;
    #pragma unroll
    for (int rf = 0; rf < 2; rf++)
      #pragma unroll
      for (int rg = 0; rg < 4; rg++) {
        const int row = rf * 16 + hi * 4 + rg;
        const float v = DLRELU(acc[rf][cf][rg] + bs);
        act[row * 256 + ((slot0 ^ (row & 7)) << 3) + (c & 7)] = f2bf(v);
      }
  }
  __syncthreads();

  #pragma unroll
  for (int L = 0; L < 2; L++) {
    const unsigned short* B = (L == 0) ? B2t : B3t;
    const float* bias = (L == 0) ? b2 : b3;
    #pragma unroll
    for (int rf = 0; rf < 2; rf++)
      #pragma unroll
      for (int cf = 0; cf < 4; cf++) acc[rf][cf] = (f32x4){0.f, 0.f, 0.f, 0.f};
    #pragma unroll
    for (int ks = 0; ks < 8; ks++) {
      short8 bv[4], av[2];
      #pragma unroll
      for (int cf = 0; cf < 4; cf++) {
        const int c = wid * 64 + cf * 16 + l15;
        bv[cf] = *reinterpret_cast<const short8*>(B + (size_t)c * 256 + ks * 32 + hi * 8);
      }
      #pragma unroll
      for (int rf = 0; rf < 2; rf++) {
        const int row = rf * 16 + l15;
        const int slot = ks * 4 + hi;
        av[rf] = *reinterpret_cast<const short8*>(
            act + row * 256 + ((slot ^ (row & 7)) << 3));
      }
      #pragma unroll
      for (int rf = 0; rf < 2; rf++)
        #pragma unroll
        for (int cf = 0; cf < 4; cf++)
          acc[rf][cf] = __builtin_amdgcn_mfma_f32_16x16x32_bf16(av[rf], bv[cf], acc[rf][cf], 0, 0, 0);
    }
    __syncthreads();
    #pragma unroll
    for (int cf = 0; cf < 4; cf++) {
      const int c = wid * 64 + cf * 16 + l15;
      const float bs = (c < 200) ? bias[c] : 0.f;
      const int slot0 = c >> 3;
      #pragma unroll
      for (int rf = 0; rf < 2; rf++)
        #pragma unroll
        for (int rg = 0; rg < 4; rg++) {
          const int row = rf * 16 + hi * 4 + rg;
          const float v = DLRELU(acc[rf][cf][rg] + bs);
          act[row * 256 + ((slot0 ^ (row & 7)) << 3) + (c & 7)] = f2bf(v);
        }
    }
    __syncthreads();
  }

  if (wid == 0) {
    f32x4 a4[2] = {};
    #pragma unroll
    for (int ks = 0; ks < 8; ks++) {
      short8 av[2];
      const short8 bv = *reinterpret_cast<const short8*>(
          B4t + (size_t)l15 * 256 + ks * 32 + hi * 8);
      #pragma unroll
      for (int rf = 0; rf < 2; rf++) {
        const int row = rf * 16 + l15;
        const int slot = ks * 4 + hi;
        av[rf] = *reinterpret_cast<const short8*>(
            act + row * 256 + ((slot ^ (row & 7)) << 3));
      }
      #pragma unroll
      for (int rf = 0; rf < 2; rf++)
        a4[rf] = __builtin_amdgcn_mfma_f32_16x16x32_bf16(av[rf], bv, a4[rf], 0, 0, 0);
    }
    if (l15 < Oo) {
      const float bs = b4[l15];
      #pragma unroll
      for (int rf = 0; rf < 2; rf++)
        #pragma unroll
        for (int rg = 0; rg < 4; rg++) {
          const int row = r0 + rf * 16 + hi * 4 + rg;
          out[(size_t)row * Oo + l15] = a4[rf][rg] + bs;
        }
    }
  }
}

// ---------------------------------------------------------------------------
extern "C" void kernel_launch(void* const* d_in, const int* in_sizes, int n_in,
                              void* d_out, int out_size, void* d_ws, size_t ws_size,
                              hipStream_t stream)
{
  const float* x     = (const float*)d_in[0];
  const int*   ei    = (const int*)d_in[1];
  const float* ea    = (const float*)d_in[2];
  const int*   batch = (const int*)d_in[3];
  const int* src = ei;
  const int* dst = ei + Ee;

  const float *We[3], *be_[3], *W1[3], *b1[3], *g_[3], *bt_[3], *mu_[3], *var_[3], *W2[3], *b2[3];
  for (int l = 0; l < 3; l++) {
    const int base = 4 + l * 10;
    We[l]  = (const float*)d_in[base + 0];
    be_[l] = (const float*)d_in[base + 1];
    W1[l]  = (const float*)d_in[base + 2];
    b1[l]  = (const float*)d_in[base + 3];
    g_[l]  = (const float*)d_in[base + 4];
    bt_[l] = (const float*)d_in[base + 5];
    mu_[l] = (const float*)d_in[base + 6];
    var_[l]= (const float*)d_in[base + 7];
    W2[l]  = (const float*)d_in[base + 8];
    b2[l]  = (const float*)d_in[base + 9];
  }
  const float *Wm[4], *bm[4];
  for (int i = 0; i < 4; i++) {
    Wm[i] = (const float*)d_in[34 + 2 * i];
    bm[i] = (const float*)d_in[35 + 2 * i];
  }

  // ---- workspace layout ----
  int* deg     = (int*)d_ws;                        // Nn
  int* cursor  = deg + Nn;                          // Nn
  int* row_ptr = cursor + Nn;                       // Nn+4
  int* bsum    = row_ptr + Nn + 4;                  // 64
  int* boff    = bsum + 64;                         // 64
  uv4* edges   = (uv4*)(boff + 64);                 // 16B aligned
  unsigned short* x0h  = (unsigned short*)(edges + Ee);  // Nn*128
  unsigned short* Wt11 = x0h + (size_t)Nn * 128;    // 256x128
  unsigned short* Wt12 = Wt11 + 32768;              // 256x256 each
  unsigned short* Wt21 = Wt12 + 65536;
  unsigned short* Wt22 = Wt21 + 65536;
  unsigned short* Wt31 = Wt22 + 65536;
  unsigned short* Wt32 = Wt31 + 65536;
  unsigned short* HW1t = Wt32 + 65536;              // 256x768 (bf16)
  unsigned short* HW2t = HW1t + 256 * 768;          // 256x256
  unsigned short* HW3t = HW2t + 65536;
  unsigned short* HW4t = HW3t + 65536;
  unsigned short* S    = HW4t + 65536;              // Nn*256
  unsigned short* XB0  = S  + (size_t)Nn * Hh;      // Nn*256
  unsigned short* XB1  = XB0 + (size_t)Nn * Hh;     // Nn*256
  float* pooled = (float*)(XB1 + (size_t)Nn * Hh);  // Gg*768
  float* outf  = (float*)d_out;

  const int  gemmGrid = (Nn + 127) / 128;
  const int  aggGrid  = (Nn + 3) / 4;
  const int  eGrid    = (Ee + 255) / 256;
  const int  sGrid    = (Nn + 1023) / 1024;

  hipMemsetAsync(deg, 0, Nn * sizeof(int), stream);
  hipMemsetAsync(pooled, 0, (size_t)Gg * 768 * sizeof(float), stream);

  // ---- consolidated prep ----
  {
    PrepArgs P;
    P.x = x; P.x0h = x0h; P.dst = dst; P.deg = deg;
    const float* s[10] = {W1[0], W2[0], W1[1], W2[1], W1[2], W2[2], Wm[0], Wm[1], Wm[2], Wm[3]};
    unsigned short* d[10] = {Wt11, Wt12, Wt21, Wt22, Wt31, Wt32, HW1t, HW2t, HW3t, HW4t};
    const int Ks[10] = {128, 256, 256, 256, 256, 256, 768, 200, 200, 200};
    const int Ms[10] = {256, 256, 256, 256, 256, 256, 200, 200, 200, 10};
    const int Kp[10] = {128, 256, 256, 256, 256, 256, 768, 256, 256, 256};
    const int bf[10] = {0, 0, 0, 0, 0, 0, 1, 1, 1, 1};
    int blk = PREP_A + PREP_B;
    for (int q = 0; q < 10; q++) {
      P.wsrc[q] = s[q]; P.wdst[q] = d[q];
      P.K[q] = Ks[q]; P.M[q] = Ms[q]; P.Kpad[q] = Kp[q]; P.isbf[q] = bf[q];
      P.blk0[q] = blk;
      blk += Kp[q];
    }
    P.blk0[10] = blk;
    prep_kernel<<<blk, 256, 0, stream>>>(P);
  }

  // CSR scan + fill (scan2 folded into scan3)
  scan1_kernel<<<sGrid, 1024, 0, stream>>>(deg, bsum);
  scan3_kernel<<<sGrid, 1024, 0, stream>>>(deg, bsum, row_ptr, cursor, sGrid);
  fill_kernel<<<eGrid, 256, 0, stream>>>(src, dst, ea, cursor, edges);

  // ---- layer 1 (din = 128) ----
  agg_gather<128><<<aggGrid, 256, 0, stream>>>(x0h, edges, We[0], be_[0], row_ptr, S);
  gemm12<128, true><<<gemmGrid, 512, 0, stream>>>(
      S, Wt11, b1[0], g_[0], bt_[0], mu_[0], var_[0], Wt12, b2[0], XB0,
      batch, pooled, 0);

  // ---- layer 2 (din = 256) ----
  agg_gather<256><<<aggGrid, 256, 0, stream>>>(XB0, edges, We[1], be_[1], row_ptr, S);
  gemm12<256, true><<<gemmGrid, 512, 0, stream>>>(
      S, Wt21, b1[1], g_[1], bt_[1], mu_[1], var_[1], Wt22, b2[1], XB1,
      batch, pooled, 1);

  // ---- layer 3 (din = 256) ----
  agg_gather<256><<<aggGrid, 256, 0, stream>>>(XB1, edges, We[2], be_[2], row_ptr, S);
  gemm12<256, false><<<gemmGrid, 512, 0, stream>>>(
      S, Wt31, b1[2], g_[2], bt_[2], mu_[2], var_[2], Wt32, b2[2], nullptr,
      batch, pooled, 2);

  // ---- fused MFMA head ----
  head_fused<<<4, 256, 0, stream>>>(pooled, HW1t, HW2t, HW3t, HW4t,
                                    bm[0], bm[1], bm[2], bm[3], outf);
}